// Round 6
// baseline (908.346 us; speedup 1.0000x reference)
//
#include <hip/hip_runtime.h>
#include <cstdint>
#include <cstddef>

// ---------- types ----------
typedef __attribute__((ext_vector_type(8))) short short8;   // 8 bf16 = 4 VGPR
typedef __attribute__((ext_vector_type(4))) float floatx4;  // MFMA C/D

#define NTOK   4096
#define NSLOT  12288     // 2*NTOK routed + NTOK shared
#define SHSLOT 8192      // shared-expert rows start here (exact top-2)
#define MAT_ELEMS (1024 * 1024)
#define NB_ROUTER 256
#define NB_PREP   (256 + 27 * 256)    // router + transpose blocks
#define NB_TOTAL  (NB_PREP + 9 * 32 * 8)

__device__ __forceinline__ unsigned short f2b(float f) {
  unsigned u = __float_as_uint(f);
  u = (u + 0x7fffu + ((u >> 16) & 1u)) >> 16;
  return (unsigned short)u;
}
__device__ __forceinline__ float b2f(unsigned short b) {
  return __uint_as_float((unsigned)b << 16);
}

// async global->LDS, 16B per lane. gsrc: per-lane address, ldst: wave-uniform base.
#define GLD16(gsrc, ldst)                                                              \
  __builtin_amdgcn_global_load_lds(                                                    \
      (const __attribute__((address_space(1))) unsigned int*)(gsrc),                   \
      (__attribute__((address_space(3))) unsigned int*)(ldst), 16, 0, 0)

__device__ __forceinline__ void expert_range(const int* __restrict__ cnt, int e,
                                             int& c, int& off) {
  if (e == 8) { c = NTOK; off = SHSLOT; return; }
  off = 0; c = 0;
#pragma unroll
  for (int i = 0; i < 8; i++) {
    int cv = cnt[i];
    if (i < e) off += cv;
    if (i == e) c = cv;
  }
}

// ---------- K1: mega-kernel = router + transpose + gateup (flag-synced) ----------
// Block roles by flat bid (dispatch order = dependency order, so no deadlock:
//   producers never wait; consumers dispatch after all producers):
//   [0,256): router (latency-bound, hidden under transpose)
//   [256,7168): transpose, ordered by matrix m (G 0-8, U 9-17, D 18-26)
//   [7168,9472): gateup, ordered by expert e; spins on {routerDone, matDone[e],
//                matDone[9+e]} then runs the R2-proven GEMM body.
// Sync: producer __syncthreads (vmcnt(0) drain) + __threadfence (L2 wb) +
//   device atomicAdd(flag); consumer atomic poll + __threadfence (L2 inv).
__global__ __launch_bounds__(256, 2) void phase1_kernel(
    const float* __restrict__ x, const float* __restrict__ Wr,
    const float* __restrict__ loopTable, const int* __restrict__ loopIdx,
    const float* __restrict__ Wg, const float* __restrict__ Wu,
    const float* __restrict__ Wd, const float* __restrict__ sg,
    const float* __restrict__ su, const float* __restrict__ sd,
    unsigned short* __restrict__ Xb, int* __restrict__ cnt,
    int* __restrict__ permSparse, float* __restrict__ wSparse,
    int2* __restrict__ tokenEPos, unsigned short* __restrict__ Wt,
    const unsigned short* __restrict__ XbRd, const unsigned short* __restrict__ WtRd,
    unsigned short* __restrict__ Hbuf) {
  // LDS union: gateup 48KB (sA/sG/sU) >= transpose 16.6KB >= router 2.2KB
  __shared__ __align__(16) char shraw[49152];
  int tid = threadIdx.x;
  int bid = blockIdx.x;
  int* flags = cnt + 16;   // [0]=routerDone, [1+m]=matDone[m] (27 used)

  if (bid < NB_ROUTER) {
    // ================= router role =================
    float (*red)[16][8] = (float(*)[16][8])shraw;
    float (*sbias)[8] = (float(*)[8])(shraw + 2048);
    int* lcnt = (int*)(shraw + 2048 + 128);
    int* lbase = (int*)(shraw + 2048 + 160);

    int lane = tid & 63;
    int seg = __builtin_amdgcn_readfirstlane(tid >> 6);
    int tok0 = bid << 4;
    int t16 = lane >> 2;
    int part = lane & 3;
    int tok = tok0 + t16;

    if (tid < 8) lcnt[tid] = 0;

    float bp[8] = {0, 0, 0, 0, 0, 0, 0, 0};
    {
      const float* emb = loopTable + (size_t)(*loopIdx) * 1024;
      int d = seg * 256 + lane * 4;
      float4 ev = *(const float4*)(emb + d);
      float es[4] = {ev.x, ev.y, ev.z, ev.w};
#pragma unroll
      for (int r = 0; r < 4; r++) {
        const float4* w4 = (const float4*)(Wr + (size_t)(1024 + d + r) * 8);
        float4 wa = w4[0], wb = w4[1];
        float e1 = es[r];
        bp[0] += e1 * wa.x; bp[1] += e1 * wa.y; bp[2] += e1 * wa.z; bp[3] += e1 * wa.w;
        bp[4] += e1 * wb.x; bp[5] += e1 * wb.y; bp[6] += e1 * wb.z; bp[7] += e1 * wb.w;
      }
    }
#pragma unroll
    for (int off = 32; off > 0; off >>= 1)
#pragma unroll
      for (int e = 0; e < 8; e++) bp[e] += __shfl_xor(bp[e], off, 64);
    if (lane == 0)
#pragma unroll
      for (int e = 0; e < 8; e++) sbias[seg][e] = bp[e];

    float lg[8] = {0, 0, 0, 0, 0, 0, 0, 0};
    const float* xr = x + (size_t)tok * 1024 + seg * 256 + part * 64;
    const float* wrb = Wr + (size_t)(seg * 256 + part * 64) * 8;
    for (int i = 0; i < 64; i += 4) {
      float4 xv = *(const float4*)(xr + i);
      float xs[4] = {xv.x, xv.y, xv.z, xv.w};
#pragma unroll
      for (int r = 0; r < 4; r++) {
        const float4* w4 = (const float4*)(wrb + (size_t)(i + r) * 8);
        float4 wa = w4[0], wb = w4[1];
        float xv1 = xs[r];
        lg[0] += xv1 * wa.x; lg[1] += xv1 * wa.y; lg[2] += xv1 * wa.z; lg[3] += xv1 * wa.w;
        lg[4] += xv1 * wb.x; lg[5] += xv1 * wb.y; lg[6] += xv1 * wb.z; lg[7] += xv1 * wb.w;
      }
    }
#pragma unroll
    for (int off = 1; off < 4; off <<= 1)
#pragma unroll
      for (int e = 0; e < 8; e++) lg[e] += __shfl_xor(lg[e], off, 64);
    if (part == 0)
#pragma unroll
      for (int e = 0; e < 8; e++) red[seg][t16][e] = lg[e];
    __syncthreads();

    int i0s = 0, i1s = 0, pos0s = 0, pos1s = 0;
    float p0s = 0.f, p1s = 0.f;
    if (tid < 16) {
      float l[8];
#pragma unroll
      for (int e = 0; e < 8; e++)
        l[e] = red[0][tid][e] + red[1][tid][e] + red[2][tid][e] + red[3][tid][e] +
               sbias[0][e] + sbias[1][e] + sbias[2][e] + sbias[3][e];
      int i0 = 0; float l0 = l[0];
#pragma unroll
      for (int e = 1; e < 8; e++) if (l[e] > l0) { l0 = l[e]; i0 = e; }
      int i1 = -1; float l1 = -1e30f;
#pragma unroll
      for (int e = 0; e < 8; e++) if (e != i0 && l[e] > l1) { l1 = l[e]; i1 = e; }
      i0s = i0; i1s = i1;
      p0s = 1.0f / (1.0f + __expf(-l0));
      p1s = 1.0f / (1.0f + __expf(-l1));
      pos0s = atomicAdd(&lcnt[i0], 1);
      pos1s = atomicAdd(&lcnt[i1], 1);
    }
    __syncthreads();
    if (tid < 8) lbase[tid] = atomicAdd(&cnt[tid], lcnt[tid]);
    __syncthreads();
    if (tid < 16) {
      int tk = tok0 + tid;
      int pos0 = lbase[i0s] + pos0s;
      int pos1 = lbase[i1s] + pos1s;
      permSparse[i0s * NTOK + pos0] = tk; wSparse[i0s * NTOK + pos0] = p0s;
      permSparse[i1s * NTOK + pos1] = tk; wSparse[i1s * NTOK + pos1] = p1s;
      tokenEPos[tk * 2 + 0] = make_int2(i0s, pos0);
      tokenEPos[tk * 2 + 1] = make_int2(i1s, pos1);
    }

    // cast 16 token rows -> bf16 (coalesced)
    const float4* xs4 = (const float4*)(x + (size_t)tok0 * 1024);
    uint2* dst = (uint2*)(Xb + (size_t)tok0 * 1024);
    for (int i = tid; i < 16 * 256; i += 256) {
      float4 v = xs4[i];
      uint2 pk;
      pk.x = (unsigned)f2b(v.x) | ((unsigned)f2b(v.y) << 16);
      pk.y = (unsigned)f2b(v.z) | ((unsigned)f2b(v.w) << 16);
      dst[i] = pk;
    }
    __syncthreads();                       // drain all global stores (vmcnt 0)
    if (tid == 0) { __threadfence(); atomicAdd(&flags[0], 1); }
    return;
  }

  if (bid < NB_PREP) {
    // ================= transpose role (R2 64x64 body) =================
    int t = bid - NB_ROUTER;          // 0..6911
    int m = t >> 8;                   // 0..26 (G 0-8, U 9-17, D 18-26)
    int tl = t & 255;
    int bn = (tl & 15) << 6;
    int bk = (tl >> 4) << 6;
    int type = m / 9, e = m % 9;
    const float* src;
    if (type == 0)      src = (e < 8) ? Wg + (size_t)e * MAT_ELEMS : sg;
    else if (type == 1) src = (e < 8) ? Wu + (size_t)e * MAT_ELEMS : su;
    else                src = (e < 8) ? Wd + (size_t)e * MAT_ELEMS : sd;

    float (*tt)[65] = (float(*)[65])shraw;
    int ln = tid & 63, lk = tid >> 6;
#pragma unroll
    for (int i = 0; i < 16; i++) {
      int k = lk + (i << 2);
      tt[k][ln] = src[(size_t)(bk + k) * 1024 + bn + ln];
    }
    __syncthreads();
    int wn = tid >> 4;
    int wk = (tid & 15) << 2;
    unsigned short* dstm = Wt + (size_t)m * MAT_ELEMS;
#pragma unroll
    for (int j = 0; j < 4; j++) {
      int n = wn + (j << 4);
      uint2 pk;
      pk.x = (unsigned)f2b(tt[wk + 0][n]) | ((unsigned)f2b(tt[wk + 1][n]) << 16);
      pk.y = (unsigned)f2b(tt[wk + 2][n]) | ((unsigned)f2b(tt[wk + 3][n]) << 16);
      *(uint2*)&dstm[(size_t)(bn + n) * 1024 + bk + wk] = pk;
    }
    __syncthreads();                       // drain global stores
    if (tid == 0) { __threadfence(); atomicAdd(&flags[1 + m], 1); }
    return;
  }

  // ================= gateup role (R2 body + flag spin) =================
  {
    int g = bid - NB_PREP;
    int gx = g & 7, gy = (g >> 3) & 31, e = g >> 8;

    // wait for router (cnt/perm/wSparse/Xb)
    if (tid == 0) {
      while (atomicAdd(&flags[0], 0) < 256) __builtin_amdgcn_s_sleep(8);
    }
    __syncthreads();
    __threadfence();                       // invalidate before reading cnt/Xb

    int c, off;
    expert_range(cnt, e, c, off);
    int m0 = gy << 7;
    if (m0 >= c) return;
    int row_base = off + m0;
    int valid_m = c - m0; if (valid_m > 128) valid_m = 128;
    int n0 = gx << 7;

    // wait for this expert's G and U transposes
    if (tid == 0) {
      while (atomicAdd(&flags[1 + e], 0) < 256) __builtin_amdgcn_s_sleep(8);
      while (atomicAdd(&flags[10 + e], 0) < 256) __builtin_amdgcn_s_sleep(8);
    }
    __syncthreads();
    __threadfence();                       // invalidate before reading Wt

    unsigned short* sA = (unsigned short*)shraw;
    unsigned short* sG = (unsigned short*)(shraw + 16384);
    unsigned short* sU = (unsigned short*)(shraw + 32768);

    int wv = tid >> 6, lane = tid & 63;
    int wm = wv >> 1, wn = wv & 1;

    const unsigned short* Gg = WtRd + (size_t)e * MAT_ELEMS + (size_t)n0 * 1024;
    const unsigned short* Ug = WtRd + (size_t)(9 + e) * MAT_ELEMS + (size_t)n0 * 1024;

    int srow = lane >> 3, schunk = lane & 7;
    int swc = (schunk ^ srow) << 3;

    int myTok[4];
#pragma unroll
    for (int j = 0; j < 4; j++) {
      int r = m0 + (wv << 5) + (j << 3) + srow;
      if (e < 8) myTok[j] = (r < c) ? permSparse[e * NTOK + r] : 0;
      else       myTok[j] = (r < c) ? r : 0;
    }

    floatx4 accG[4][4], accU[4][4];
#pragma unroll
    for (int i = 0; i < 4; i++)
#pragma unroll
      for (int j = 0; j < 4; j++) {
        accG[i][j] = floatx4{0.f, 0.f, 0.f, 0.f};
        accU[i][j] = floatx4{0.f, 0.f, 0.f, 0.f};
      }

    for (int kk = 0; kk < 1024; kk += 64) {
      __syncthreads();
#pragma unroll
      for (int j = 0; j < 4; j++) {
        int rb = (wv << 5) + (j << 3);
        size_t gw = (size_t)(rb + srow) * 1024 + kk + swc;
        GLD16(XbRd + (size_t)myTok[j] * 1024 + kk + swc, &sA[rb * 64]);
        GLD16(Gg + gw, &sG[rb * 64]);
        GLD16(Ug + gw, &sU[rb * 64]);
      }
      __syncthreads();
#pragma unroll
      for (int k0 = 0; k0 < 64; k0 += 32) {
        int swoff = (((lane >> 4) + (k0 >> 3)) ^ (lane & 7)) << 3;
        int arow = (wm << 6) + (lane & 15);
        short8 af[4];
#pragma unroll
        for (int mi = 0; mi < 4; mi++)
          af[mi] = *(const short8*)&sA[(arow + (mi << 4)) * 64 + swoff];
        int brow = (wn << 6) + (lane & 15);
#pragma unroll
        for (int ni = 0; ni < 4; ni++) {
          short8 gf = *(const short8*)&sG[(brow + (ni << 4)) * 64 + swoff];
          short8 uf = *(const short8*)&sU[(brow + (ni << 4)) * 64 + swoff];
#pragma unroll
          for (int mi = 0; mi < 4; mi++) {
            accG[mi][ni] = __builtin_amdgcn_mfma_f32_16x16x32_bf16(af[mi], gf, accG[mi][ni], 0, 0, 0);
            accU[mi][ni] = __builtin_amdgcn_mfma_f32_16x16x32_bf16(af[mi], uf, accU[mi][ni], 0, 0, 0);
          }
        }
      }
    }

    int colLane = lane & 15, quad = lane >> 4;
#pragma unroll
    for (int mi = 0; mi < 4; mi++) {
#pragma unroll
      for (int reg = 0; reg < 4; reg++) {
        int mrow = (wm << 6) + (mi << 4) + (quad << 2) + reg;
        if (mrow < valid_m) {
          int r = m0 + mrow;
          float w = (e < 8) ? wSparse[e * NTOK + r] : 1.0f;
          unsigned short* hr = Hbuf + (size_t)(row_base + mrow) * 1024 + n0 + (wn << 6) + colLane;
#pragma unroll
          for (int ni = 0; ni < 4; ni++) {
            float gg2 = accG[mi][ni][reg];
            float u = accU[mi][ni][reg];
            float hh = (gg2 / (1.0f + __expf(-gg2))) * u * w;
            hr[ni << 4] = f2b(hh);
          }
        }
      }
    }
  }
}

// ---------- K4: down projection GEMM (R2-proven body) ----------
__global__ __launch_bounds__(256, 2) void down_gemm(
    const unsigned short* __restrict__ Hbuf, const unsigned short* __restrict__ Wt,
    const int* __restrict__ cnt, unsigned short* __restrict__ Dbuf) {
  int e = blockIdx.z;
  int c, off;
  expert_range(cnt, e, c, off);
  int m0 = blockIdx.y << 7;
  if (m0 >= c) return;
  int row_base = off + m0;
  int valid_m = c - m0; if (valid_m > 128) valid_m = 128;
  int n0 = blockIdx.x << 7;

  __shared__ unsigned short sA[128 * 64];
  __shared__ unsigned short sB[128 * 64];

  int tid = threadIdx.x;
  int wv = tid >> 6, lane = tid & 63;
  int wm = wv >> 1, wn = wv & 1;

  const unsigned short* Ag = Hbuf + (size_t)row_base * 1024;
  const unsigned short* Bg = Wt + (size_t)(18 + e) * MAT_ELEMS + (size_t)n0 * 1024;

  int srow = lane >> 3, schunk = lane & 7;
  int swc = (schunk ^ srow) << 3;

  floatx4 acc[4][4];
#pragma unroll
  for (int i = 0; i < 4; i++)
#pragma unroll
    for (int j = 0; j < 4; j++) acc[i][j] = floatx4{0.f, 0.f, 0.f, 0.f};

  for (int kk = 0; kk < 1024; kk += 64) {
    __syncthreads();
#pragma unroll
    for (int j = 0; j < 4; j++) {
      int rb = (wv << 5) + (j << 3);
      size_t gw = (size_t)(rb + srow) * 1024 + kk + swc;
      GLD16(Ag + gw, &sA[rb * 64]);
      GLD16(Bg + gw, &sB[rb * 64]);
    }
    __syncthreads();
#pragma unroll
    for (int k0 = 0; k0 < 64; k0 += 32) {
      int swoff = (((lane >> 4) + (k0 >> 3)) ^ (lane & 7)) << 3;
      int arow = (wm << 6) + (lane & 15);
      short8 af[4];
#pragma unroll
      for (int mi = 0; mi < 4; mi++)
        af[mi] = *(const short8*)&sA[(arow + (mi << 4)) * 64 + swoff];
      int brow = (wn << 6) + (lane & 15);
#pragma unroll
      for (int ni = 0; ni < 4; ni++) {
        short8 bf = *(const short8*)&sB[(brow + (ni << 4)) * 64 + swoff];
#pragma unroll
        for (int mi = 0; mi < 4; mi++)
          acc[mi][ni] = __builtin_amdgcn_mfma_f32_16x16x32_bf16(af[mi], bf, acc[mi][ni], 0, 0, 0);
      }
    }
  }

  int colLane = lane & 15, quad = lane >> 4;
#pragma unroll
  for (int mi = 0; mi < 4; mi++) {
#pragma unroll
    for (int reg = 0; reg < 4; reg++) {
      int mrow = (wm << 6) + (mi << 4) + (quad << 2) + reg;
      if (mrow < valid_m) {
        unsigned short* dr = Dbuf + (size_t)(row_base + mrow) * 1024 + n0 + (wn << 6) + colLane;
#pragma unroll
        for (int ni = 0; ni < 4; ni++)
          dr[ni << 4] = f2b(acc[mi][ni][reg]);
      }
    }
  }
}

// ---------- K5: combine shared + 2 routed rows -> out (fp32) ----------
__global__ __launch_bounds__(256) void combine_kernel(
    const unsigned short* __restrict__ Dbuf, const int* __restrict__ cnt,
    const int2* __restrict__ tokenEPos, float* __restrict__ out) {
  __shared__ int soffs[8];
  if (threadIdx.x == 0) {
    int s = 0;
    for (int i = 0; i < 8; i++) { soffs[i] = s; s += cnt[i]; }
  }
  __syncthreads();
  int tok = (blockIdx.x << 1) + (threadIdx.x >> 7);
  int lane = threadIdx.x & 127;
  int2 a = tokenEPos[tok * 2 + 0];
  int2 b = tokenEPos[tok * 2 + 1];
  int s0 = soffs[a.x] + a.y;
  int s1 = soffs[b.x] + b.y;
  int ssh = SHSLOT + tok;
  int d = lane << 3;
  uint4 r0 = *(const uint4*)(Dbuf + (size_t)ssh * 1024 + d);
  uint4 r1 = *(const uint4*)(Dbuf + (size_t)s0 * 1024 + d);
  uint4 r2 = *(const uint4*)(Dbuf + (size_t)s1 * 1024 + d);
  float o[8];
  const unsigned* u0 = (const unsigned*)&r0;
  const unsigned* u1 = (const unsigned*)&r1;
  const unsigned* u2 = (const unsigned*)&r2;
#pragma unroll
  for (int i = 0; i < 4; i++) {
    o[2 * i + 0] = b2f((unsigned short)(u0[i] & 0xffff)) +
                   b2f((unsigned short)(u1[i] & 0xffff)) +
                   b2f((unsigned short)(u2[i] & 0xffff));
    o[2 * i + 1] = b2f((unsigned short)(u0[i] >> 16)) +
                   b2f((unsigned short)(u1[i] >> 16)) +
                   b2f((unsigned short)(u2[i] >> 16));
  }
  float* orow = out + (size_t)tok * 1024 + d;
  *(float4*)(orow + 0) = make_float4(o[0], o[1], o[2], o[3]);
  *(float4*)(orow + 4) = make_float4(o[4], o[5], o[6], o[7]);
}

// ---------- launch ----------
extern "C" void kernel_launch(void* const* d_in, const int* in_sizes, int n_in,
                              void* d_out, int out_size, void* d_ws, size_t ws_size,
                              hipStream_t stream) {
  const float* x  = (const float*)d_in[0];
  const float* sg = (const float*)d_in[1];
  const float* su = (const float*)d_in[2];
  const float* sd = (const float*)d_in[3];
  const float* Wg = (const float*)d_in[4];
  const float* Wu = (const float*)d_in[5];
  const float* Wd = (const float*)d_in[6];
  const float* Wr = (const float*)d_in[7];
  const float* loopTable = (const float*)d_in[8];
  const int*   loopIdx   = (const int*)d_in[9];
  float* out = (float*)d_out;

  char* w = (char*)d_ws;
  unsigned short* Wt = (unsigned short*)w;    w += (size_t)27 * MAT_ELEMS * 2;
  unsigned short* Xb = (unsigned short*)w;    w += (size_t)NTOK * 1024 * 2;
  unsigned short* Hbuf = (unsigned short*)w;  w += (size_t)NSLOT * 1024 * 2;
  unsigned short* Dbuf = (unsigned short*)w;  w += (size_t)NSLOT * 1024 * 2;
  int*   cnt        = (int*)w;   w += 48 * 4;   // 16 cnt + 32 flags
  int*   permSparse = (int*)w;   w += (size_t)8 * NTOK * 4;
  float* wSparse    = (float*)w; w += (size_t)8 * NTOK * 4;
  int2*  tokenEPos  = (int2*)w;  w += (size_t)NTOK * 2 * 8;

  hipMemsetAsync(cnt, 0, 192, stream);   // zero cnt + flags
  // mega-kernel: router -> transpose (by matrix) -> gateup (by expert),
  // flag-synced; gateup overlaps the transpose tail.
  phase1_kernel<<<NB_TOTAL, 256, 0, stream>>>(
      x, Wr, loopTable, loopIdx, Wg, Wu, Wd, sg, su, sd,
      Xb, cnt, permSparse, wSparse, tokenEPos, Wt,
      Xb, Wt, Hbuf);
  down_gemm<<<dim3(8, 32, 9), 256, 0, stream>>>(Hbuf, Wt, cnt, Dbuf);
  combine_kernel<<<2048, 256, 0, stream>>>(Dbuf, cnt, tokenEPos, out);
}

// Round 7
// 289.864 us; speedup vs baseline: 3.1337x; 3.1337x over previous
//
#include <hip/hip_runtime.h>
#include <cstdint>
#include <cstddef>

// ---------- types ----------
typedef __attribute__((ext_vector_type(8))) short short8;   // 8 bf16 = 4 VGPR
typedef __attribute__((ext_vector_type(4))) float floatx4;  // MFMA C/D

#define NTOK   4096
#define NSLOT  12288     // 2*NTOK routed + NTOK shared
#define SHSLOT 8192      // shared-expert rows start here (exact top-2)
#define MAT_ELEMS (1024 * 1024)

__device__ __forceinline__ unsigned short f2b(float f) {
  unsigned u = __float_as_uint(f);
  u = (u + 0x7fffu + ((u >> 16) & 1u)) >> 16;
  return (unsigned short)u;
}
__device__ __forceinline__ float b2f(unsigned short b) {
  return __uint_as_float((unsigned)b << 16);
}

// async global->LDS, 16B per lane. gsrc: per-lane address, ldst: wave-uniform base.
#define GLD16(gsrc, ldst)                                                              \
  __builtin_amdgcn_global_load_lds(                                                    \
      (const __attribute__((address_space(1))) unsigned int*)(gsrc),                   \
      (__attribute__((address_space(3))) unsigned int*)(ldst), 16, 0, 0)

// ---------- K1: fused prep = router (z==0, dispatched FIRST) + transpose (z>=1) ----
// Router role: 256 latency-bound blocks dispatch first, co-reside with the
//   BW-bound transpose blocks that fill the CUs behind them (hiding ~25us).
// Transpose role: R0-proven body — scalar 4B coalesced loads (256B/row/wave),
//   t[64][65] fp32 tile (2-way max bank aliasing = free), uint2 bf16 stores.
__global__ __launch_bounds__(256) void prep_kernel(
    const float* __restrict__ x, const float* __restrict__ Wr,
    const float* __restrict__ loopTable, const int* __restrict__ loopIdx,
    const float* __restrict__ Wg, const float* __restrict__ Wu,
    const float* __restrict__ Wd, const float* __restrict__ sg,
    const float* __restrict__ su, const float* __restrict__ sd,
    unsigned short* __restrict__ Xb, int* __restrict__ cnt,
    int* __restrict__ permSparse, float* __restrict__ wSparse,
    int2* __restrict__ tokenEPos, unsigned short* __restrict__ Wt) {
  // LDS overlay: transpose tile (16640B) unions with router scratch (2240B)
  __shared__ __align__(16) char shraw[64 * 65 * 4];
  float (*t)[65] = (float(*)[65])shraw;                 // transpose
  float (*red)[16][8] = (float(*)[16][8])shraw;          // router: [4][16][8]
  float (*sbias)[8] = (float(*)[8])(shraw + 2048);       // [4][8]
  int* lcnt = (int*)(shraw + 2048 + 128);                // [8]
  int* lbase = (int*)(shraw + 2048 + 160);               // [8]

  int tid = threadIdx.x;

  if (blockIdx.z != 0) {
    // ---------------- transpose role (R0 body verbatim) ----------------
    int m = blockIdx.z - 1;  // 0..26
    int type = m / 9, e = m % 9;
    const float* src;
    if (type == 0)      src = (e < 8) ? Wg + (size_t)e * MAT_ELEMS : sg;
    else if (type == 1) src = (e < 8) ? Wu + (size_t)e * MAT_ELEMS : su;
    else                src = (e < 8) ? Wd + (size_t)e * MAT_ELEMS : sd;
    int bn = blockIdx.x << 6;  // n (out) base
    int bk = blockIdx.y << 6;  // k (in) base
    int ln = tid & 63, lk = tid >> 6;
#pragma unroll
    for (int i = 0; i < 16; i++) {
      int k = lk + (i << 2);
      t[k][ln] = src[(size_t)(bk + k) * 1024 + bn + ln];
    }
    __syncthreads();
    int wn = tid >> 4;          // 0..15
    int wk = (tid & 15) << 2;   // 4 bf16 per thread = 8B
    unsigned short* dstm = Wt + (size_t)m * MAT_ELEMS;
#pragma unroll
    for (int j = 0; j < 4; j++) {
      int n = wn + (j << 4);
      uint2 pk;
      pk.x = (unsigned)f2b(t[wk + 0][n]) | ((unsigned)f2b(t[wk + 1][n]) << 16);
      pk.y = (unsigned)f2b(t[wk + 2][n]) | ((unsigned)f2b(t[wk + 3][n]) << 16);
      *(uint2*)&dstm[(size_t)(bn + n) * 1024 + bk + wk] = pk;
    }
    return;
  }

  // ---------------- router role (z==0: dispatched before all transpose) -------
  int bid = (blockIdx.y << 4) | blockIdx.x;   // 0..255
  int lane = tid & 63;
  int seg = __builtin_amdgcn_readfirstlane(tid >> 6);
  int tok0 = bid << 4;
  int t16 = lane >> 2;   // token in block
  int part = lane & 3;   // 64-dim quarter of the wave's 256-dim segment
  int tok = tok0 + t16;

  if (tid < 8) lcnt[tid] = 0;

  // bias partial: loop_emb @ Wr[1024:]; wave seg covers 256 dims, lane covers 4
  float bp[8] = {0, 0, 0, 0, 0, 0, 0, 0};
  {
    const float* emb = loopTable + (size_t)(*loopIdx) * 1024;
    int d = seg * 256 + lane * 4;
    float4 ev = *(const float4*)(emb + d);
    float es[4] = {ev.x, ev.y, ev.z, ev.w};
#pragma unroll
    for (int r = 0; r < 4; r++) {
      const float4* w4 = (const float4*)(Wr + (size_t)(1024 + d + r) * 8);
      float4 wa = w4[0], wb = w4[1];
      float e1 = es[r];
      bp[0] += e1 * wa.x; bp[1] += e1 * wa.y; bp[2] += e1 * wa.z; bp[3] += e1 * wa.w;
      bp[4] += e1 * wb.x; bp[5] += e1 * wb.y; bp[6] += e1 * wb.z; bp[7] += e1 * wb.w;
    }
  }
#pragma unroll
  for (int off = 32; off > 0; off >>= 1)
#pragma unroll
    for (int e = 0; e < 8; e++) bp[e] += __shfl_xor(bp[e], off, 64);
  if (lane == 0)
#pragma unroll
    for (int e = 0; e < 8; e++) sbias[seg][e] = bp[e];

  // logits partial: lane covers dims seg*256 + part*64 + [0,64)
  float lg[8] = {0, 0, 0, 0, 0, 0, 0, 0};
  const float* xr = x + (size_t)tok * 1024 + seg * 256 + part * 64;
  const float* wrb = Wr + (size_t)(seg * 256 + part * 64) * 8;
  for (int i = 0; i < 64; i += 4) {
    float4 xv = *(const float4*)(xr + i);
    float xs[4] = {xv.x, xv.y, xv.z, xv.w};
#pragma unroll
    for (int r = 0; r < 4; r++) {
      const float4* w4 = (const float4*)(wrb + (size_t)(i + r) * 8);
      float4 wa = w4[0], wb = w4[1];
      float xv1 = xs[r];
      lg[0] += xv1 * wa.x; lg[1] += xv1 * wa.y; lg[2] += xv1 * wa.z; lg[3] += xv1 * wa.w;
      lg[4] += xv1 * wb.x; lg[5] += xv1 * wb.y; lg[6] += xv1 * wb.z; lg[7] += xv1 * wb.w;
    }
  }
  // reduce over the 4 parts (aligned quads)
#pragma unroll
  for (int off = 1; off < 4; off <<= 1)
#pragma unroll
    for (int e = 0; e < 8; e++) lg[e] += __shfl_xor(lg[e], off, 64);
  if (part == 0)
#pragma unroll
    for (int e = 0; e < 8; e++) red[seg][t16][e] = lg[e];
  __syncthreads();

  int i0s = 0, i1s = 0, pos0s = 0, pos1s = 0;
  float p0s = 0.f, p1s = 0.f;
  if (tid < 16) {
    float l[8];
#pragma unroll
    for (int e = 0; e < 8; e++)
      l[e] = red[0][tid][e] + red[1][tid][e] + red[2][tid][e] + red[3][tid][e] +
             sbias[0][e] + sbias[1][e] + sbias[2][e] + sbias[3][e];
    int i0 = 0; float l0 = l[0];
#pragma unroll
    for (int e = 1; e < 8; e++) if (l[e] > l0) { l0 = l[e]; i0 = e; }
    int i1 = -1; float l1 = -1e30f;
#pragma unroll
    for (int e = 0; e < 8; e++) if (e != i0 && l[e] > l1) { l1 = l[e]; i1 = e; }
    i0s = i0; i1s = i1;
    p0s = 1.0f / (1.0f + __expf(-l0));
    p1s = 1.0f / (1.0f + __expf(-l1));
    pos0s = atomicAdd(&lcnt[i0], 1);
    pos1s = atomicAdd(&lcnt[i1], 1);
  }
  __syncthreads();
  if (tid < 8) lbase[tid] = atomicAdd(&cnt[tid], lcnt[tid]);
  __syncthreads();
  if (tid < 16) {
    int tk = tok0 + tid;
    int pos0 = lbase[i0s] + pos0s;
    int pos1 = lbase[i1s] + pos1s;
    permSparse[i0s * NTOK + pos0] = tk; wSparse[i0s * NTOK + pos0] = p0s;
    permSparse[i1s * NTOK + pos1] = tk; wSparse[i1s * NTOK + pos1] = p1s;
    tokenEPos[tk * 2 + 0] = make_int2(i0s, pos0);
    tokenEPos[tk * 2 + 1] = make_int2(i1s, pos1);
  }

  // cast 16 token rows -> bf16 (coalesced)
  const float4* xs4 = (const float4*)(x + (size_t)tok0 * 1024);
  uint2* dst = (uint2*)(Xb + (size_t)tok0 * 1024);
  for (int i = tid; i < 16 * 256; i += 256) {
    float4 v = xs4[i];
    uint2 pk;
    pk.x = (unsigned)f2b(v.x) | ((unsigned)f2b(v.y) << 16);
    pk.y = (unsigned)f2b(v.z) | ((unsigned)f2b(v.w) << 16);
    dst[i] = pk;
  }
}

__device__ __forceinline__ void expert_range(const int* __restrict__ cnt, int e,
                                             int& c, int& off) {
  if (e == 8) { c = NTOK; off = SHSLOT; return; }
  off = 0; c = 0;
#pragma unroll
  for (int i = 0; i < 8; i++) {
    int cv = cnt[i];
    if (i < e) off += cv;
    if (i == e) c = cv;
  }
}

// ---------- K3: fused gate+up GEMM + silu*up*weight -> bf16 h ----------
// XOR chunk swizzle + launch_bounds(256,2) (R5-verified: conflicts 0, no spill).
__global__ __launch_bounds__(256, 2) void gateup_gemm(
    const unsigned short* __restrict__ Xb, const unsigned short* __restrict__ Wt,
    const int* __restrict__ cnt, const int* __restrict__ permSparse,
    const float* __restrict__ wSparse, unsigned short* __restrict__ Hbuf) {
  int e = blockIdx.z;
  int c, off;
  expert_range(cnt, e, c, off);
  int m0 = blockIdx.y << 7;
  if (m0 >= c) return;
  int row_base = off + m0;
  int valid_m = c - m0; if (valid_m > 128) valid_m = 128;
  int n0 = blockIdx.x << 7;

  __shared__ unsigned short sA[128 * 64];
  __shared__ unsigned short sG[128 * 64];
  __shared__ unsigned short sU[128 * 64];

  int tid = threadIdx.x;
  int wv = tid >> 6, lane = tid & 63;
  int wm = wv >> 1, wn = wv & 1;

  const unsigned short* Gg = Wt + (size_t)e * MAT_ELEMS + (size_t)n0 * 1024;
  const unsigned short* Ug = Wt + (size_t)(9 + e) * MAT_ELEMS + (size_t)n0 * 1024;

  int srow = lane >> 3, schunk = lane & 7;
  int swc = (schunk ^ srow) << 3;   // swizzled k-chunk (elements) for staging

  int myTok[4];
#pragma unroll
  for (int j = 0; j < 4; j++) {
    int r = m0 + (wv << 5) + (j << 3) + srow;
    if (e < 8) myTok[j] = (r < c) ? permSparse[e * NTOK + r] : 0;
    else       myTok[j] = (r < c) ? r : 0;
  }

  floatx4 accG[4][4], accU[4][4];
#pragma unroll
  for (int i = 0; i < 4; i++)
#pragma unroll
    for (int j = 0; j < 4; j++) {
      accG[i][j] = floatx4{0.f, 0.f, 0.f, 0.f};
      accU[i][j] = floatx4{0.f, 0.f, 0.f, 0.f};
    }

  for (int kk = 0; kk < 1024; kk += 64) {
    __syncthreads();
#pragma unroll
    for (int j = 0; j < 4; j++) {
      int rb = (wv << 5) + (j << 3);
      size_t gw = (size_t)(rb + srow) * 1024 + kk + swc;
      GLD16(Xb + (size_t)myTok[j] * 1024 + kk + swc, &sA[rb * 64]);
      GLD16(Gg + gw, &sG[rb * 64]);
      GLD16(Ug + gw, &sU[rb * 64]);
    }
    __syncthreads();
#pragma unroll
    for (int k0 = 0; k0 < 64; k0 += 32) {
      int swoff = (((lane >> 4) + (k0 >> 3)) ^ (lane & 7)) << 3;  // logical chunk ^ row&7
      int arow = (wm << 6) + (lane & 15);
      short8 af[4];
#pragma unroll
      for (int mi = 0; mi < 4; mi++)
        af[mi] = *(const short8*)&sA[(arow + (mi << 4)) * 64 + swoff];
      int brow = (wn << 6) + (lane & 15);
#pragma unroll
      for (int ni = 0; ni < 4; ni++) {
        short8 gf = *(const short8*)&sG[(brow + (ni << 4)) * 64 + swoff];
        short8 uf = *(const short8*)&sU[(brow + (ni << 4)) * 64 + swoff];
#pragma unroll
        for (int mi = 0; mi < 4; mi++) {
          accG[mi][ni] = __builtin_amdgcn_mfma_f32_16x16x32_bf16(af[mi], gf, accG[mi][ni], 0, 0, 0);
          accU[mi][ni] = __builtin_amdgcn_mfma_f32_16x16x32_bf16(af[mi], uf, accU[mi][ni], 0, 0, 0);
        }
      }
    }
  }

  int colLane = lane & 15, quad = lane >> 4;
#pragma unroll
  for (int mi = 0; mi < 4; mi++) {
#pragma unroll
    for (int reg = 0; reg < 4; reg++) {
      int mrow = (wm << 6) + (mi << 4) + (quad << 2) + reg;
      if (mrow < valid_m) {
        int r = m0 + mrow;
        float w = (e < 8) ? wSparse[e * NTOK + r] : 1.0f;
        unsigned short* hr = Hbuf + (size_t)(row_base + mrow) * 1024 + n0 + (wn << 6) + colLane;
#pragma unroll
        for (int ni = 0; ni < 4; ni++) {
          float g = accG[mi][ni][reg];
          float u = accU[mi][ni][reg];
          float h = (g / (1.0f + __expf(-g))) * u * w;
          hr[ni << 4] = f2b(h);
        }
      }
    }
  }
}

// ---------- K4: down projection GEMM -> bf16 Dbuf[slot] (no atomics) ----------
__global__ __launch_bounds__(256, 2) void down_gemm(
    const unsigned short* __restrict__ Hbuf, const unsigned short* __restrict__ Wt,
    const int* __restrict__ cnt, unsigned short* __restrict__ Dbuf) {
  int e = blockIdx.z;
  int c, off;
  expert_range(cnt, e, c, off);
  int m0 = blockIdx.y << 7;
  if (m0 >= c) return;
  int row_base = off + m0;
  int valid_m = c - m0; if (valid_m > 128) valid_m = 128;
  int n0 = blockIdx.x << 7;

  __shared__ unsigned short sA[128 * 64];
  __shared__ unsigned short sB[128 * 64];

  int tid = threadIdx.x;
  int wv = tid >> 6, lane = tid & 63;
  int wm = wv >> 1, wn = wv & 1;

  const unsigned short* Ag = Hbuf + (size_t)row_base * 1024;
  const unsigned short* Bg = Wt + (size_t)(18 + e) * MAT_ELEMS + (size_t)n0 * 1024;

  int srow = lane >> 3, schunk = lane & 7;
  int swc = (schunk ^ srow) << 3;

  floatx4 acc[4][4];
#pragma unroll
  for (int i = 0; i < 4; i++)
#pragma unroll
    for (int j = 0; j < 4; j++) acc[i][j] = floatx4{0.f, 0.f, 0.f, 0.f};

  for (int kk = 0; kk < 1024; kk += 64) {
    __syncthreads();
#pragma unroll
    for (int j = 0; j < 4; j++) {
      int rb = (wv << 5) + (j << 3);
      size_t gw = (size_t)(rb + srow) * 1024 + kk + swc;
      GLD16(Ag + gw, &sA[rb * 64]);
      GLD16(Bg + gw, &sB[rb * 64]);
    }
    __syncthreads();
#pragma unroll
    for (int k0 = 0; k0 < 64; k0 += 32) {
      int swoff = (((lane >> 4) + (k0 >> 3)) ^ (lane & 7)) << 3;
      int arow = (wm << 6) + (lane & 15);
      short8 af[4];
#pragma unroll
      for (int mi = 0; mi < 4; mi++)
        af[mi] = *(const short8*)&sA[(arow + (mi << 4)) * 64 + swoff];
      int brow = (wn << 6) + (lane & 15);
#pragma unroll
      for (int ni = 0; ni < 4; ni++) {
        short8 bf = *(const short8*)&sB[(brow + (ni << 4)) * 64 + swoff];
#pragma unroll
        for (int mi = 0; mi < 4; mi++)
          acc[mi][ni] = __builtin_amdgcn_mfma_f32_16x16x32_bf16(af[mi], bf, acc[mi][ni], 0, 0, 0);
      }
    }
  }

  int colLane = lane & 15, quad = lane >> 4;
#pragma unroll
  for (int mi = 0; mi < 4; mi++) {
#pragma unroll
    for (int reg = 0; reg < 4; reg++) {
      int mrow = (wm << 6) + (mi << 4) + (quad << 2) + reg;
      if (mrow < valid_m) {
        unsigned short* dr = Dbuf + (size_t)(row_base + mrow) * 1024 + n0 + (wn << 6) + colLane;
#pragma unroll
        for (int ni = 0; ni < 4; ni++)
          dr[ni << 4] = f2b(acc[mi][ni][reg]);
      }
    }
  }
}

// ---------- K5: combine shared + 2 routed rows -> out (fp32) ----------
__global__ __launch_bounds__(256) void combine_kernel(
    const unsigned short* __restrict__ Dbuf, const int* __restrict__ cnt,
    const int2* __restrict__ tokenEPos, float* __restrict__ out) {
  __shared__ int soffs[8];
  if (threadIdx.x == 0) {
    int s = 0;
    for (int i = 0; i < 8; i++) { soffs[i] = s; s += cnt[i]; }
  }
  __syncthreads();
  int tok = (blockIdx.x << 1) + (threadIdx.x >> 7);
  int lane = threadIdx.x & 127;            // 128 threads/token, 8 elems each
  int2 a = tokenEPos[tok * 2 + 0];
  int2 b = tokenEPos[tok * 2 + 1];
  int s0 = soffs[a.x] + a.y;
  int s1 = soffs[b.x] + b.y;
  int ssh = SHSLOT + tok;
  int d = lane << 3;
  uint4 r0 = *(const uint4*)(Dbuf + (size_t)ssh * 1024 + d);
  uint4 r1 = *(const uint4*)(Dbuf + (size_t)s0 * 1024 + d);
  uint4 r2 = *(const uint4*)(Dbuf + (size_t)s1 * 1024 + d);
  float o[8];
  const unsigned* u0 = (const unsigned*)&r0;
  const unsigned* u1 = (const unsigned*)&r1;
  const unsigned* u2 = (const unsigned*)&r2;
#pragma unroll
  for (int i = 0; i < 4; i++) {
    o[2 * i + 0] = b2f((unsigned short)(u0[i] & 0xffff)) +
                   b2f((unsigned short)(u1[i] & 0xffff)) +
                   b2f((unsigned short)(u2[i] & 0xffff));
    o[2 * i + 1] = b2f((unsigned short)(u0[i] >> 16)) +
                   b2f((unsigned short)(u1[i] >> 16)) +
                   b2f((unsigned short)(u2[i] >> 16));
  }
  float* orow = out + (size_t)tok * 1024 + d;
  *(float4*)(orow + 0) = make_float4(o[0], o[1], o[2], o[3]);
  *(float4*)(orow + 4) = make_float4(o[4], o[5], o[6], o[7]);
}

// ---------- launch ----------
extern "C" void kernel_launch(void* const* d_in, const int* in_sizes, int n_in,
                              void* d_out, int out_size, void* d_ws, size_t ws_size,
                              hipStream_t stream) {
  const float* x  = (const float*)d_in[0];
  const float* sg = (const float*)d_in[1];
  const float* su = (const float*)d_in[2];
  const float* sd = (const float*)d_in[3];
  const float* Wg = (const float*)d_in[4];
  const float* Wu = (const float*)d_in[5];
  const float* Wd = (const float*)d_in[6];
  const float* Wr = (const float*)d_in[7];
  const float* loopTable = (const float*)d_in[8];
  const int*   loopIdx   = (const int*)d_in[9];
  float* out = (float*)d_out;

  char* w = (char*)d_ws;
  unsigned short* Wt = (unsigned short*)w;    w += (size_t)27 * MAT_ELEMS * 2;
  unsigned short* Xb = (unsigned short*)w;    w += (size_t)NTOK * 1024 * 2;
  unsigned short* Hbuf = (unsigned short*)w;  w += (size_t)NSLOT * 1024 * 2;
  unsigned short* Dbuf = (unsigned short*)w;  w += (size_t)NSLOT * 1024 * 2;
  int*   cnt        = (int*)w;   w += 16 * 4;
  int*   permSparse = (int*)w;   w += (size_t)8 * NTOK * 4;
  float* wSparse    = (float*)w; w += (size_t)8 * NTOK * 4;
  int2*  tokenEPos  = (int2*)w;  w += (size_t)NTOK * 2 * 8;

  hipMemsetAsync(cnt, 0, 32, stream);
  // fused: router at z==0 dispatches FIRST (hidden under transpose z=1..27)
  prep_kernel<<<dim3(16, 16, 28), 256, 0, stream>>>(
      x, Wr, loopTable, loopIdx, Wg, Wu, Wd, sg, su, sd,
      Xb, cnt, permSparse, wSparse, tokenEPos, Wt);
  gateup_gemm<<<dim3(8, 32, 9), 256, 0, stream>>>(Xb, Wt, cnt, permSparse,
                                                  wSparse, Hbuf);
  down_gemm<<<dim3(8, 32, 9), 256, 0, stream>>>(Hbuf, Wt, cnt, Dbuf);
  combine_kernel<<<2048, 256, 0, stream>>>(Dbuf, cnt, tokenEPos, out);
}